// Round 4
// baseline (748.869 us; speedup 1.0000x reference)
//
#include <hip/hip_runtime.h>
#include <cstddef>
#include <cstdint>

#define B_  64
#define T_  51
#define H_  512
#define G4_ 2048
#define V_  32000
#define R_  (T_ * B_)   // 3264
#define RED_STRIDE 20   // floats; 80B, 16B-aligned, odd-mult-of-4 word stride

typedef __attribute__((ext_vector_type(8))) short bf16x8;
typedef __attribute__((ext_vector_type(4))) float f32x4;
typedef unsigned long long ull;

__device__ __forceinline__ uint16_t f2bf(float f) {   // RNE float->bf16
    uint32_t u = __float_as_uint(f);
    u += 0x7FFFu + ((u >> 16) & 1u);
    return (uint16_t)(u >> 16);
}
__device__ __forceinline__ float bf2f(uint32_t h) {
    return __uint_as_float(h << 16);
}

// ---------------------------------------------------------------- K0: init
// hx = bf16(x); sumexp = 0; flags = 0   (ws not re-poisoned between replays)
__global__ __launch_bounds__(256) void k0_init(const float* __restrict__ x,
                                               uint16_t* __restrict__ hx,
                                               float* __restrict__ sumexp,
                                               int* __restrict__ flags) {
    int i = blockIdx.x * 256 + threadIdx.x;
    if (i < B_ * H_) hx[i] = f2bf(x[i]);
    if (i < R_) sumexp[i] = 0.f;
    if (i < T_ * 32) flags[i] = 0;
}

// ---------------------------------------------------------------- Kcvt: f32 -> bf16
__global__ __launch_bounds__(256) void kcvt(const float* __restrict__ src,
                                            uint16_t* __restrict__ dst, int n8) {
    int i = blockIdx.x * 256 + threadIdx.x;
    if (i >= n8) return;
    const float4* s = (const float4*)src + (size_t)i * 2;
    float4 f0 = s[0], f1 = s[1];
    union { uint16_t h[8]; uint4 u; } p;
    p.h[0]=f2bf(f0.x); p.h[1]=f2bf(f0.y); p.h[2]=f2bf(f0.z); p.h[3]=f2bf(f0.w);
    p.h[4]=f2bf(f1.x); p.h[5]=f2bf(f1.y); p.h[6]=f2bf(f1.z); p.h[7]=f2bf(f1.w);
    ((uint4*)dst)[i] = p.u;
}

// ---------------------------------------------------------------- K1: Xg GEMM (bf16 MFMA)
// XgT[((t*512+u)*4+g)*64+b] = bf16( emb[tok(r)].W_ih[g*512+u] + b_ih + b_hh )
// tile 64x256, BK=64, grid (8 n-tiles, 51 t).
template<int CVT>
__global__ __launch_bounds__(256, 2) void k1_mfma(const int* __restrict__ labels,
                                                  const float* __restrict__ emb,
                                                  const void* __restrict__ wih,
                                                  const float* __restrict__ b_ih,
                                                  const float* __restrict__ b_hh,
                                                  uint16_t* __restrict__ XgT) {
    __shared__ uint16_t Al[64 * 72];
    __shared__ uint16_t Bl[256 * 72];
    const int t    = blockIdx.y;
    const int n0   = blockIdx.x * 256;
    const int tid  = threadIdx.x;
    const int w    = tid >> 6;
    const int lane = tid & 63;
    const int l15  = lane & 15;
    const int lhi  = lane >> 4;

    f32x4 acc[4][4];
    #pragma unroll
    for (int mi = 0; mi < 4; ++mi)
        #pragma unroll
        for (int nf = 0; nf < 4; ++nf) acc[mi][nf] = (f32x4){0.f, 0.f, 0.f, 0.f};

    for (int k0 = 0; k0 < H_; k0 += 64) {
        #pragma unroll
        for (int r = 0; r < 2; ++r) {       // A: 64 rows x 64, gather+convert
            int idx = r * 256 + tid, row = idx >> 3, seg = idx & 7;
            int tok = (t == 0) ? 1 : labels[row * 50 + (t - 1)];
            const float* s = emb + (size_t)tok * H_ + k0 + seg * 8;
            float4 f0 = *(const float4*)s;
            float4 f1 = *(const float4*)(s + 4);
            union { uint16_t h[8]; uint4 u; } p;
            p.h[0]=f2bf(f0.x); p.h[1]=f2bf(f0.y); p.h[2]=f2bf(f0.z); p.h[3]=f2bf(f0.w);
            p.h[4]=f2bf(f1.x); p.h[5]=f2bf(f1.y); p.h[6]=f2bf(f1.z); p.h[7]=f2bf(f1.w);
            *(uint4*)(Al + row * 72 + seg * 8) = p.u;
        }
        #pragma unroll
        for (int r = 0; r < 8; ++r) {       // B: 256 rows x 64
            int idx = r * 256 + tid, row = idx >> 3, seg = idx & 7;
            if (CVT) {
                const float* s = (const float*)wih + (size_t)(n0 + row) * H_ + k0 + seg * 8;
                float4 f0 = *(const float4*)s;
                float4 f1 = *(const float4*)(s + 4);
                union { uint16_t h[8]; uint4 u; } p;
                p.h[0]=f2bf(f0.x); p.h[1]=f2bf(f0.y); p.h[2]=f2bf(f0.z); p.h[3]=f2bf(f0.w);
                p.h[4]=f2bf(f1.x); p.h[5]=f2bf(f1.y); p.h[6]=f2bf(f1.z); p.h[7]=f2bf(f1.w);
                *(uint4*)(Bl + row * 72 + seg * 8) = p.u;
            } else {
                *(uint4*)(Bl + row * 72 + seg * 8) =
                    *(const uint4*)((const uint16_t*)wih + (size_t)(n0 + row) * H_ + k0 + seg * 8);
            }
        }
        __syncthreads();
        #pragma unroll
        for (int ks = 0; ks < 2; ++ks) {
            bf16x8 a[4];
            #pragma unroll
            for (int mi = 0; mi < 4; ++mi)
                a[mi] = *(const bf16x8*)(Al + (mi * 16 + l15) * 72 + ks * 32 + lhi * 8);
            #pragma unroll
            for (int nf = 0; nf < 4; ++nf) {
                bf16x8 b = *(const bf16x8*)(Bl + (w * 64 + nf * 16 + l15) * 72 + ks * 32 + lhi * 8);
                #pragma unroll
                for (int mi = 0; mi < 4; ++mi)
                    acc[mi][nf] = __builtin_amdgcn_mfma_f32_16x16x32_bf16(a[mi], b, acc[mi][nf], 0, 0, 0);
            }
        }
        __syncthreads();
    }
    float bias[4];
    #pragma unroll
    for (int nf = 0; nf < 4; ++nf) {
        int col = n0 + w * 64 + nf * 16 + l15;
        bias[nf] = b_ih[col] + b_hh[col];
    }
    #pragma unroll
    for (int mi = 0; mi < 4; ++mi)
        #pragma unroll
        for (int nf = 0; nf < 4; ++nf) {
            const int col = n0 + w * 64 + nf * 16 + l15;
            const int g = col >> 9, u = col & 511;
            const int b = mi * 16 + lhi * 4;
            union { uint16_t h[4]; ull q; } pk;
            #pragma unroll
            for (int q = 0; q < 4; ++q) pk.h[q] = f2bf(acc[mi][nf][q] + bias[nf]);
            *(ull*)(XgT + ((size_t)(t * 512 + u) * 4 + g) * 64 + b) = pk.q;
        }
}

// ---------------------------------------------------------------- K2p: persistent LSTM
// 32 blocks x 512 threads. Block owns 16 units; W_hh slice bf16 LDS-resident.
// Waves 0-3: m-frag w, ks 0-7.  Waves 4-7: same m-frags, ks 8-15 -> LDS-reduce.
// h exchange: agent relaxed atomics (LLC-coherent). Barrier: distributed flags
// (one store per block, 32 lanes poll all flags in parallel -> no RMW contention).
__global__ __launch_bounds__(512) void k2p(const uint16_t* __restrict__ hx,
                                           const float* __restrict__ x,
                                           const uint16_t* __restrict__ XgT,
                                           const float* __restrict__ W_hh,
                                           uint16_t* __restrict__ hs,
                                           int* __restrict__ flags) {
    extern __shared__ uint16_t lds2[];
    uint16_t* Wl  = lds2;                          // 64*520 u16 = 66560 B
    float*    red = (float*)(lds2 + 64 * 520);     // 256*20 f32 = 20480 B
    const int tid  = threadIdx.x;
    const int bid  = blockIdx.x;
    const int u0   = bid * 16;
    const int w    = tid >> 6;
    const int lane = tid & 63;
    const int l15  = lane & 15;
    const int lhi  = lane >> 4;
    const int mf   = w & 3;       // m-frag (rows mf*16..+15)
    const int kh   = w >> 2;      // k-half (ks 0-7 or 8-15)

    {   // W_hh slice -> bf16 LDS. LDS row c = g*16+uu <-> W row g*512+u0+uu
        const int c  = tid >> 3;
        const int q8 = tid & 7;
        const int j  = (c >> 4) * 512 + u0 + (c & 15);
        const float* src = W_hh + (size_t)j * H_ + q8 * 64;
        uint16_t* dst = Wl + c * 520 + q8 * 64;
        #pragma unroll
        for (int i = 0; i < 64; i += 8) {
            float4 f0 = *(const float4*)(src + i);
            float4 f1 = *(const float4*)(src + i + 4);
            union { uint16_t h[8]; uint4 u; } p;
            p.h[0]=f2bf(f0.x); p.h[1]=f2bf(f0.y); p.h[2]=f2bf(f0.z); p.h[3]=f2bf(f0.w);
            p.h[4]=f2bf(f1.x); p.h[5]=f2bf(f1.y); p.h[6]=f2bf(f1.z); p.h[7]=f2bf(f1.w);
            *(uint4*)(dst + i) = p.u;
        }
    }
    float cst[4] = {0.f, 0.f, 0.f, 0.f};
    ull   xgp[4] = {0, 0, 0, 0};
    if (kh == 0) {
        #pragma unroll
        for (int q = 0; q < 4; ++q)
            cst[q] = x[(size_t)(mf * 16 + lhi * 4 + q) * H_ + u0 + l15];
        #pragma unroll
        for (int g = 0; g < 4; ++g)     // prefetch XgT for t=0
            xgp[g] = *(const ull*)(XgT + ((size_t)(0 * 512 + u0 + l15) * 4 + g) * 64 + mf * 16 + lhi * 4);
    }
    __syncthreads();

    for (int t = 0; t < T_; ++t) {
        const uint16_t* hp = (t == 0) ? hx : hs + (size_t)(t - 1) * B_ * H_;
        const int arow = mf * 16 + l15;
        ull ha[8][2];
        #pragma unroll
        for (int ks2 = 0; ks2 < 8; ++ks2) {
            const ull* p = (const ull*)(hp + (size_t)arow * H_ + (kh * 8 + ks2) * 32 + lhi * 8);
            ha[ks2][0] = __hip_atomic_load(p,     __ATOMIC_RELAXED, __HIP_MEMORY_SCOPE_AGENT);
            ha[ks2][1] = __hip_atomic_load(p + 1, __ATOMIC_RELAXED, __HIP_MEMORY_SCOPE_AGENT);
        }
        f32x4 acc[4];
        #pragma unroll
        for (int nf = 0; nf < 4; ++nf) acc[nf] = (f32x4){0.f, 0.f, 0.f, 0.f};
        #pragma unroll
        for (int ks2 = 0; ks2 < 8; ++ks2) {
            union { ull q[2]; bf16x8 v; } au;
            au.q[0] = ha[ks2][0]; au.q[1] = ha[ks2][1];
            #pragma unroll
            for (int nf = 0; nf < 4; ++nf) {
                bf16x8 b = *(const bf16x8*)(Wl + (nf * 16 + l15) * 520 + (kh * 8 + ks2) * 32 + lhi * 8);
                acc[nf] = __builtin_amdgcn_mfma_f32_16x16x32_bf16(au.v, b, acc[nf], 0, 0, 0);
            }
        }
        if (kh == 1) {      // publish k-half-1 partials
            const int slot = mf * 64 + lane;
            #pragma unroll
            for (int nf = 0; nf < 4; ++nf)
                *(f32x4*)(red + slot * RED_STRIDE + nf * 4) = acc[nf];
        }
        __syncthreads();    // A: partials visible
        if (kh == 0) {
            const int slot = mf * 64 + lane;
            #pragma unroll
            for (int nf = 0; nf < 4; ++nf) {
                f32x4 pv = *(const f32x4*)(red + slot * RED_STRIDE + nf * 4);
                acc[nf] += pv;
            }
            #pragma unroll
            for (int q = 0; q < 4; ++q) {
                float gi = acc[0][q] + bf2f((uint32_t)((xgp[0] >> (16 * q)) & 0xFFFF));
                float gf = acc[1][q] + bf2f((uint32_t)((xgp[1] >> (16 * q)) & 0xFFFF));
                float gg = acc[2][q] + bf2f((uint32_t)((xgp[2] >> (16 * q)) & 0xFFFF));
                float go = acc[3][q] + bf2f((uint32_t)((xgp[3] >> (16 * q)) & 0xFFFF));
                float si = 1.f / (1.f + __expf(-gi));
                float sf = 1.f / (1.f + __expf(-gf));
                float tg = tanhf(gg);
                float so = 1.f / (1.f + __expf(-go));
                float cc = sf * cst[q] + si * tg;
                cst[q] = cc;
                uint16_t hv = f2bf(so * tanhf(cc));
                __hip_atomic_store(hs + (size_t)(t * 64 + mf * 16 + lhi * 4 + q) * H_ + u0 + l15, hv,
                                   __ATOMIC_RELAXED, __HIP_MEMORY_SCOPE_AGENT);
            }
            if (t + 1 < T_) {   // prefetch next step's gate biases (race-free data)
                #pragma unroll
                for (int g = 0; g < 4; ++g)
                    xgp[g] = *(const ull*)(XgT + ((size_t)((t + 1) * 512 + u0 + l15) * 4 + g) * 64 + mf * 16 + lhi * 4);
            }
        }
        __syncthreads();    // B: all h-stores drained (vmcnt(0) per wave before barrier)
        if (tid < 32) {
            if (tid == 0)
                __hip_atomic_store(&flags[t * 32 + bid], 1, __ATOMIC_RELAXED, __HIP_MEMORY_SCOPE_AGENT);
            while (__hip_atomic_load(&flags[t * 32 + tid], __ATOMIC_RELAXED, __HIP_MEMORY_SCOPE_AGENT) == 0)
                __builtin_amdgcn_s_sleep(1);
        }
        __syncthreads();    // C: release; next-step loads issue after this
    }
}

// ---------------------------------------------------------------- K3: FC + lse (bf16 MFMA)
// tile 128x256, BK=64, 4 waves. 2-phase reg-prefetch (CVT=0): k+1 panel loads
// issued right after staging barrier, latency hides under 64 MFMA/wave.
// 1D grid 3250, bijective XCD swizzle (each XCD sweeps contiguous fc_W slice).
template<int CVT>
__global__ __launch_bounds__(256, 2) void k3_mfma(const uint16_t* __restrict__ hsb,
                                                  const void* __restrict__ fcw,
                                                  const float* __restrict__ fc_b,
                                                  const int* __restrict__ labels,
                                                  float* __restrict__ sumexp,
                                                  float* __restrict__ tgtlog) {
    __shared__ uint16_t Al[128 * 72];
    __shared__ uint16_t Bl[256 * 72];
    const int flat = blockIdx.x;        // 3250 = 8*406+2: xcd 0,1 get 407
    const int xcd  = flat & 7;
    const int slot = flat >> 3;
    const int work = (xcd < 2 ? xcd * 407 : 814 + (xcd - 2) * 406) + slot;
    const int m0   = (work % 26) * 128;
    const int v0   = (work / 26) * 256;
    const int tid  = threadIdx.x;
    const int w    = tid >> 6;
    const int lane = tid & 63;
    const int l15  = lane & 15;
    const int lhi  = lane >> 4;

    f32x4 acc[8][4];
    #pragma unroll
    for (int mi = 0; mi < 8; ++mi)
        #pragma unroll
        for (int nf = 0; nf < 4; ++nf) acc[mi][nf] = (f32x4){0.f, 0.f, 0.f, 0.f};

    if (CVT) {
        // fallback: serial stage+convert (fp32 fc_W)
        for (int k0 = 0; k0 < H_; k0 += 64) {
            #pragma unroll
            for (int r = 0; r < 4; ++r) {
                int idx = r * 256 + tid, row = idx >> 3, seg = idx & 7;
                int grow = m0 + row; if (grow >= R_) grow = R_ - 1;
                *(uint4*)(Al + row * 72 + seg * 8) =
                    *(const uint4*)(hsb + (size_t)grow * H_ + k0 + seg * 8);
            }
            #pragma unroll
            for (int r = 0; r < 8; ++r) {
                int idx = r * 256 + tid, row = idx >> 3, seg = idx & 7;
                const float* s = (const float*)fcw + (size_t)(v0 + row) * H_ + k0 + seg * 8;
                float4 f0 = *(const float4*)s;
                float4 f1 = *(const float4*)(s + 4);
                union { uint16_t h[8]; uint4 u; } p;
                p.h[0]=f2bf(f0.x); p.h[1]=f2bf(f0.y); p.h[2]=f2bf(f0.z); p.h[3]=f2bf(f0.w);
                p.h[4]=f2bf(f1.x); p.h[5]=f2bf(f1.y); p.h[6]=f2bf(f1.z); p.h[7]=f2bf(f1.w);
                *(uint4*)(Bl + row * 72 + seg * 8) = p.u;
            }
            __syncthreads();
            #pragma unroll
            for (int ks = 0; ks < 2; ++ks) {
                bf16x8 a[8];
                #pragma unroll
                for (int mi = 0; mi < 8; ++mi)
                    a[mi] = *(const bf16x8*)(Al + (mi * 16 + l15) * 72 + ks * 32 + lhi * 8);
                #pragma unroll
                for (int nf = 0; nf < 4; ++nf) {
                    bf16x8 b = *(const bf16x8*)(Bl + (w * 64 + nf * 16 + l15) * 72 + ks * 32 + lhi * 8);
                    #pragma unroll
                    for (int mi = 0; mi < 8; ++mi)
                        acc[mi][nf] = __builtin_amdgcn_mfma_f32_16x16x32_bf16(a[mi], b, acc[mi][nf], 0, 0, 0);
                }
            }
            __syncthreads();
        }
    } else {
        const uint16_t* fw = (const uint16_t*)fcw;
        int growm[4];
        #pragma unroll
        for (int r = 0; r < 4; ++r) {
            int idx = r * 256 + tid, row = idx >> 3;
            growm[r] = (m0 + row >= R_) ? (R_ - 1) : (m0 + row);
        }
        uint4 arA[4], arB[8];
        #pragma unroll
        for (int r = 0; r < 4; ++r) {
            int idx = r * 256 + tid, seg = idx & 7;
            arA[r] = *(const uint4*)(hsb + (size_t)growm[r] * H_ + seg * 8);
        }
        #pragma unroll
        for (int r = 0; r < 8; ++r) {
            int idx = r * 256 + tid, row = idx >> 3, seg = idx & 7;
            arB[r] = *(const uint4*)(fw + (size_t)(v0 + row) * H_ + seg * 8);
        }
        #pragma unroll
        for (int k0 = 0; k0 < 8; ++k0) {
            #pragma unroll
            for (int r = 0; r < 4; ++r) {
                int idx = r * 256 + tid, row = idx >> 3, seg = idx & 7;
                *(uint4*)(Al + row * 72 + seg * 8) = arA[r];
            }
            #pragma unroll
            for (int r = 0; r < 8; ++r) {
                int idx = r * 256 + tid, row = idx >> 3, seg = idx & 7;
                *(uint4*)(Bl + row * 72 + seg * 8) = arB[r];
            }
            __syncthreads();
            if (k0 < 7) {   // prefetch k0+1 panels; latency hides under MFMA
                const int kk = (k0 + 1) * 64;
                #pragma unroll
                for (int r = 0; r < 4; ++r) {
                    int idx = r * 256 + tid, seg = idx & 7;
                    arA[r] = *(const uint4*)(hsb + (size_t)growm[r] * H_ + kk + seg * 8);
                }
                #pragma unroll
                for (int r = 0; r < 8; ++r) {
                    int idx = r * 256 + tid, row = idx >> 3, seg = idx & 7;
                    arB[r] = *(const uint4*)(fw + (size_t)(v0 + row) * H_ + kk + seg * 8);
                }
            }
            #pragma unroll
            for (int ks = 0; ks < 2; ++ks) {
                bf16x8 a[8];
                #pragma unroll
                for (int mi = 0; mi < 8; ++mi)
                    a[mi] = *(const bf16x8*)(Al + (mi * 16 + l15) * 72 + ks * 32 + lhi * 8);
                #pragma unroll
                for (int nf = 0; nf < 4; ++nf) {
                    bf16x8 b = *(const bf16x8*)(Bl + (w * 64 + nf * 16 + l15) * 72 + ks * 32 + lhi * 8);
                    #pragma unroll
                    for (int mi = 0; mi < 8; ++mi)
                        acc[mi][nf] = __builtin_amdgcn_mfma_f32_16x16x32_bf16(a[mi], b, acc[mi][nf], 0, 0, 0);
                }
            }
            __syncthreads();
        }
    }
    // epilogue: bias + exp-sum (16-lane shuffle reduce) + target-logit pick
    float bias[4];
    #pragma unroll
    for (int nf = 0; nf < 4; ++nf) bias[nf] = fc_b[v0 + w * 64 + nf * 16 + l15];
    #pragma unroll
    for (int mi = 0; mi < 8; ++mi) {
        #pragma unroll
        for (int q = 0; q < 4; ++q) {
            const int r = m0 + mi * 16 + lhi * 4 + q;
            if (r >= R_) continue;
            const int t = r >> 6, b = r & 63;
            const int tgt = (t < 50) ? labels[b * 50 + t] : 2;
            float lsum = 0.f;
            #pragma unroll
            for (int nf = 0; nf < 4; ++nf) {
                const int v = v0 + w * 64 + nf * 16 + l15;
                float lg = acc[mi][nf][q] + bias[nf];
                lsum += __expf(lg);
                if (v == tgt) tgtlog[r] = lg;
            }
            lsum += __shfl_xor(lsum, 1, 16);
            lsum += __shfl_xor(lsum, 2, 16);
            lsum += __shfl_xor(lsum, 4, 16);
            lsum += __shfl_xor(lsum, 8, 16);
            if (l15 == 0) atomicAdd(&sumexp[r], lsum);
        }
    }
}

// ---------------------------------------------------------------- K4: loss
__global__ __launch_bounds__(256) void k4_loss(const float* __restrict__ sumexp,
                                               const float* __restrict__ tgtlog,
                                               float* __restrict__ out) {
    __shared__ float red[256];
    float s = 0.f;
    for (int r = threadIdx.x; r < R_; r += 256) s += logf(sumexp[r]) - tgtlog[r];
    red[threadIdx.x] = s;
    __syncthreads();
    for (int st = 128; st > 0; st >>= 1) {
        if (threadIdx.x < st) red[threadIdx.x] += red[threadIdx.x + st];
        __syncthreads();
    }
    if (threadIdx.x == 0) out[0] = red[0] / 64.0f;
}

// ----------------------------------------------------------------
extern "C" void kernel_launch(void* const* d_in, const int* in_sizes, int n_in,
                              void* d_out, int out_size, void* d_ws, size_t ws_size,
                              hipStream_t stream) {
    const float* x      = (const float*)d_in[0];
    const int*   labels = (const int*)d_in[1];
    const float* emb    = (const float*)d_in[2];
    const float* W_ih   = (const float*)d_in[3];
    const float* W_hh   = (const float*)d_in[4];
    const float* b_ih   = (const float*)d_in[5];
    const float* b_hh   = (const float*)d_in[6];
    const float* fc_W   = (const float*)d_in[7];
    const float* fc_b   = (const float*)d_in[8];
    float* out = (float*)d_out;

    char* p = (char*)d_ws;
    uint16_t* XgT    = (uint16_t*)p;  p += (size_t)T_ * 512 * 4 * 64 * 2;  // 13.4 MB
    uint16_t* hsb    = (uint16_t*)p;  p += (size_t)R_ * H_ * 2;            // 3.3 MB
    uint16_t* hx     = (uint16_t*)p;  p += (size_t)B_ * H_ * 2;
    float*    sumexp = (float*)p;     p += (size_t)R_ * 4;
    float*    tgtl   = (float*)p;     p += (size_t)R_ * 4;
    int*      flags  = (int*)p;       p += 8192;
    uint16_t* fcwb   = (uint16_t*)p;  p += (size_t)V_ * H_ * 2;            // 32.8 MB
    uint16_t* wihb   = (uint16_t*)p;  p += (size_t)G4_ * H_ * 2;           // 2.1 MB
    const bool pre = ((size_t)(p - (char*)d_ws) <= ws_size);

    k0_init<<<128, 256, 0, stream>>>(x, hx, sumexp, flags);
    if (pre) {
        kcvt<<<8000, 256, 0, stream>>>(fc_W, fcwb, (V_ * H_) / 8);
        kcvt<<<512, 256, 0, stream>>>(W_ih, wihb, (G4_ * H_) / 8);
        k1_mfma<0><<<dim3(8, 51), 256, 0, stream>>>(labels, emb, wihb, b_ih, b_hh, XgT);
    } else {
        k1_mfma<1><<<dim3(8, 51), 256, 0, stream>>>(labels, emb, W_ih, b_ih, b_hh, XgT);
    }
    k2p<<<32, 512, 64 * 520 * 2 + 256 * RED_STRIDE * 4, stream>>>(hx, x, XgT, W_hh, hsb, flags);
    if (pre) k3_mfma<0><<<3250, 256, 0, stream>>>(hsb, fcwb, fc_b, labels, sumexp, tgtl);
    else     k3_mfma<1><<<3250, 256, 0, stream>>>(hsb, fc_W, fc_b, labels, sumexp, tgtl);
    k4_loss<<<1, 256, 0, stream>>>(sumexp, tgtl, out);
}

// Round 5
// 710.597 us; speedup vs baseline: 1.0539x; 1.0539x over previous
//
#include <hip/hip_runtime.h>
#include <cstddef>
#include <cstdint>

#define B_  64
#define T_  51
#define H_  512
#define G4_ 2048
#define V_  32000
#define R_  (T_ * B_)   // 3264

typedef __attribute__((ext_vector_type(8))) short bf16x8;
typedef __attribute__((ext_vector_type(4))) float f32x4;
typedef __attribute__((ext_vector_type(4))) unsigned int u32x4;
typedef unsigned long long ull;

__device__ __forceinline__ uint16_t f2bf(float f) {   // RNE float->bf16
    uint32_t u = __float_as_uint(f);
    u += 0x7FFFu + ((u >> 16) & 1u);
    return (uint16_t)(u >> 16);
}
__device__ __forceinline__ float bf2f(uint32_t h) { return __uint_as_float(h << 16); }

// LLC-coherent load/store (bypass L1+L2, operate at the device coherence point)
__device__ __forceinline__ void ldsc(u32x4& d, const uint32_t* p) {
    asm volatile("global_load_dwordx4 %0, %1, off sc0 sc1" : "=v"(d) : "v"(p));
}
__device__ __forceinline__ void stsc(uint32_t* p, uint32_t v) {
    asm volatile("global_store_dword %0, %1, off sc0 sc1" :: "v"(p), "v"(v) : "memory");
}
#define TIE4(a,b,c,d) asm volatile("" : "+v"(a), "+v"(b), "+v"(c), "+v"(d))

// async global->LDS, 16B per lane, linear dest (wave-uniform base + lane*16)
__device__ __forceinline__ void gl_lds16(const void* g, void* l) {
    __builtin_amdgcn_global_load_lds((const __attribute__((address_space(1))) void*)g,
                                     (__attribute__((address_space(3))) void*)l, 16, 0, 0);
}

// ---------------------------------------------------------------- K0: init
// hx = bf16(x); sumexp = 0; hp32 (epoch exchange buffer) = 0. grid 256x256.
__global__ __launch_bounds__(256) void k0_init(const float* __restrict__ x,
                                               uint16_t* __restrict__ hx,
                                               float* __restrict__ sumexp,
                                               uint32_t* __restrict__ hp32) {
    int i = blockIdx.x * 256 + threadIdx.x;      // 0..65535
    if (i < B_ * H_) hx[i] = f2bf(x[i]);
    if (i < R_) sumexp[i] = 0.f;
    hp32[i] = 0;                                  // 2*64*512 = 65536 words
}

// ---------------------------------------------------------------- Kcvt: f32 -> bf16
__global__ __launch_bounds__(256) void kcvt(const float* __restrict__ src,
                                            uint16_t* __restrict__ dst, int n8) {
    int i = blockIdx.x * 256 + threadIdx.x;
    if (i >= n8) return;
    const float4* s = (const float4*)src + (size_t)i * 2;
    float4 f0 = s[0], f1 = s[1];
    union { uint16_t h[8]; uint4 u; } p;
    p.h[0]=f2bf(f0.x); p.h[1]=f2bf(f0.y); p.h[2]=f2bf(f0.z); p.h[3]=f2bf(f0.w);
    p.h[4]=f2bf(f1.x); p.h[5]=f2bf(f1.y); p.h[6]=f2bf(f1.z); p.h[7]=f2bf(f1.w);
    ((uint4*)dst)[i] = p.u;
}

// ---------------------------------------------------------------- K1: Xg GEMM (bf16 MFMA)
// XgT[((t*512+u)*4+g)*64+b] = bf16( emb[tok(r)].W_ih[g*512+u] + b_ih + b_hh )
template<int CVT>
__global__ __launch_bounds__(256, 2) void k1_mfma(const int* __restrict__ labels,
                                                  const float* __restrict__ emb,
                                                  const void* __restrict__ wih,
                                                  const float* __restrict__ b_ih,
                                                  const float* __restrict__ b_hh,
                                                  uint16_t* __restrict__ XgT) {
    __shared__ uint16_t Al[64 * 72];
    __shared__ uint16_t Bl[256 * 72];
    const int t    = blockIdx.y;
    const int n0   = blockIdx.x * 256;
    const int tid  = threadIdx.x;
    const int w    = tid >> 6;
    const int lane = tid & 63;
    const int l15  = lane & 15;
    const int lhi  = lane >> 4;

    f32x4 acc[4][4];
    #pragma unroll
    for (int mi = 0; mi < 4; ++mi)
        #pragma unroll
        for (int nf = 0; nf < 4; ++nf) acc[mi][nf] = (f32x4){0.f, 0.f, 0.f, 0.f};

    for (int k0 = 0; k0 < H_; k0 += 64) {
        #pragma unroll
        for (int r = 0; r < 2; ++r) {       // A: 64x64, gather+convert
            int idx = r * 256 + tid, row = idx >> 3, seg = idx & 7;
            int tok = (t == 0) ? 1 : labels[row * 50 + (t - 1)];
            const float* s = emb + (size_t)tok * H_ + k0 + seg * 8;
            float4 f0 = *(const float4*)s;
            float4 f1 = *(const float4*)(s + 4);
            union { uint16_t h[8]; uint4 u; } p;
            p.h[0]=f2bf(f0.x); p.h[1]=f2bf(f0.y); p.h[2]=f2bf(f0.z); p.h[3]=f2bf(f0.w);
            p.h[4]=f2bf(f1.x); p.h[5]=f2bf(f1.y); p.h[6]=f2bf(f1.z); p.h[7]=f2bf(f1.w);
            *(uint4*)(Al + row * 72 + seg * 8) = p.u;
        }
        #pragma unroll
        for (int r = 0; r < 8; ++r) {       // B: 256x64
            int idx = r * 256 + tid, row = idx >> 3, seg = idx & 7;
            if (CVT) {
                const float* s = (const float*)wih + (size_t)(n0 + row) * H_ + k0 + seg * 8;
                float4 f0 = *(const float4*)s;
                float4 f1 = *(const float4*)(s + 4);
                union { uint16_t h[8]; uint4 u; } p;
                p.h[0]=f2bf(f0.x); p.h[1]=f2bf(f0.y); p.h[2]=f2bf(f0.z); p.h[3]=f2bf(f0.w);
                p.h[4]=f2bf(f1.x); p.h[5]=f2bf(f1.y); p.h[6]=f2bf(f1.z); p.h[7]=f2bf(f1.w);
                *(uint4*)(Bl + row * 72 + seg * 8) = p.u;
            } else {
                *(uint4*)(Bl + row * 72 + seg * 8) =
                    *(const uint4*)((const uint16_t*)wih + (size_t)(n0 + row) * H_ + k0 + seg * 8);
            }
        }
        __syncthreads();
        #pragma unroll
        for (int ks = 0; ks < 2; ++ks) {
            bf16x8 a[4];
            #pragma unroll
            for (int mi = 0; mi < 4; ++mi)
                a[mi] = *(const bf16x8*)(Al + (mi * 16 + l15) * 72 + ks * 32 + lhi * 8);
            #pragma unroll
            for (int nf = 0; nf < 4; ++nf) {
                bf16x8 b = *(const bf16x8*)(Bl + (w * 64 + nf * 16 + l15) * 72 + ks * 32 + lhi * 8);
                #pragma unroll
                for (int mi = 0; mi < 4; ++mi)
                    acc[mi][nf] = __builtin_amdgcn_mfma_f32_16x16x32_bf16(a[mi], b, acc[mi][nf], 0, 0, 0);
            }
        }
        __syncthreads();
    }
    float bias[4];
    #pragma unroll
    for (int nf = 0; nf < 4; ++nf) {
        int col = n0 + w * 64 + nf * 16 + l15;
        bias[nf] = b_ih[col] + b_hh[col];
    }
    #pragma unroll
    for (int mi = 0; mi < 4; ++mi)
        #pragma unroll
        for (int nf = 0; nf < 4; ++nf) {
            const int col = n0 + w * 64 + nf * 16 + l15;
            const int g = col >> 9, u = col & 511;
            const int b = mi * 16 + lhi * 4;
            union { uint16_t h[4]; ull q; } pk;
            #pragma unroll
            for (int q = 0; q < 4; ++q) pk.h[q] = f2bf(acc[mi][nf][q] + bias[nf]);
            *(ull*)(XgT + ((size_t)(t * 512 + u) * 4 + g) * 64 + b) = pk.q;
        }
}

// ---------------------------------------------------------------- K2p: persistent LSTM
// 32 blocks x 256 thr. Block owns 16 units (u0..u0+15); wave w owns batch rows
// w*16..w*16+15 -> waves are fully independent (no intra-block sync in loop).
// Cross-block h exchange: epoch-tagged u32 words ((t+1)<<16 | bf16) in a
// ping-pong LLC buffer; sc0 sc1 write-through stores / pipelined dwordx4 loads
// with retry until all 128 epoch fields match. No flags, no fences, no atomics.
__global__ __launch_bounds__(256, 1) void k2p(const uint16_t* __restrict__ hx,
                                              const float* __restrict__ x,
                                              const uint16_t* __restrict__ XgT,
                                              const float* __restrict__ W_hh,
                                              uint16_t* __restrict__ hs,
                                              uint32_t* __restrict__ hp32) {
    __shared__ uint16_t Wl[64 * 520];
    const int tid  = threadIdx.x;
    const int u0   = blockIdx.x * 16;
    const int w    = tid >> 6;
    const int lane = tid & 63;
    const int l15  = lane & 15;
    const int lhi  = lane >> 4;
    const int arow = w * 16 + l15;      // A-frag batch row

    {   // W_hh slice -> bf16 LDS. LDS row c = g*16+uu <-> W row g*512+u0+uu
        const int c = tid >> 2;
        const int q = tid & 3;
        const int j = (c >> 4) * 512 + u0 + (c & 15);
        const float* src = W_hh + (size_t)j * H_ + q * 128;
        uint16_t* dst = Wl + c * 520 + q * 128;
        #pragma unroll
        for (int i = 0; i < 128; i += 8) {
            float4 f0 = *(const float4*)(src + i);
            float4 f1 = *(const float4*)(src + i + 4);
            union { uint16_t h[8]; uint4 u; } p;
            p.h[0]=f2bf(f0.x); p.h[1]=f2bf(f0.y); p.h[2]=f2bf(f0.z); p.h[3]=f2bf(f0.w);
            p.h[4]=f2bf(f1.x); p.h[5]=f2bf(f1.y); p.h[6]=f2bf(f1.z); p.h[7]=f2bf(f1.w);
            *(uint4*)(dst + i) = p.u;
        }
    }
    float cst[4];
    #pragma unroll
    for (int q = 0; q < 4; ++q)
        cst[q] = x[(size_t)(w * 16 + lhi * 4 + q) * H_ + u0 + l15];
    __syncthreads();                    // Wl ready (read-only afterwards)

    u32x4 ha[16];                       // A-frags: 16 x bf16x8
    for (int t = 0; t < T_; ++t) {
        if (t == 0) {
            const uint16_t* hb = hx + (size_t)arow * H_ + lhi * 8;
            #pragma unroll
            for (int ks = 0; ks < 16; ++ks)
                ha[ks] = *(const u32x4*)(hb + ks * 32);
        } else {
            const uint32_t* hb = hp32 + ((t - 1) & 1) * (B_ * H_) + arow * H_ + lhi * 8;
            const uint32_t et = (uint32_t)t << 16;
            for (;;) {
                u32x4 raw[16][2];
                #pragma unroll
                for (int ks = 0; ks < 16; ++ks) {
                    ldsc(raw[ks][0], hb + ks * 32);
                    ldsc(raw[ks][1], hb + ks * 32 + 4);
                }
                asm volatile("s_waitcnt vmcnt(0)" ::: "memory");
                #pragma unroll
                for (int ks = 0; ks < 16; ks += 2) {
                    TIE4(raw[ks][0], raw[ks][1], raw[ks+1][0], raw[ks+1][1]);
                }
                uint32_t bad = 0;
                #pragma unroll
                for (int ks = 0; ks < 16; ++ks)
                    #pragma unroll
                    for (int h = 0; h < 2; ++h) {
                        bad |= (raw[ks][h][0] ^ et) & 0xFFFF0000u;
                        bad |= (raw[ks][h][1] ^ et) & 0xFFFF0000u;
                        bad |= (raw[ks][h][2] ^ et) & 0xFFFF0000u;
                        bad |= (raw[ks][h][3] ^ et) & 0xFFFF0000u;
                    }
                if (__any((int)(bad != 0))) continue;
                #pragma unroll
                for (int ks = 0; ks < 16; ++ks) {
                    ha[ks][0] = (raw[ks][0][0] & 0xFFFFu) | (raw[ks][0][1] << 16);
                    ha[ks][1] = (raw[ks][0][2] & 0xFFFFu) | (raw[ks][0][3] << 16);
                    ha[ks][2] = (raw[ks][1][0] & 0xFFFFu) | (raw[ks][1][1] << 16);
                    ha[ks][3] = (raw[ks][1][2] & 0xFFFFu) | (raw[ks][1][3] << 16);
                }
                break;
            }
        }
        // gate biases (race-free, L2-cached)
        ull xgp[4];
        #pragma unroll
        for (int g = 0; g < 4; ++g)
            xgp[g] = *(const ull*)(XgT + ((size_t)(t * 512 + u0 + l15) * 4 + g) * 64 + w * 16 + lhi * 4);

        f32x4 acc[4];
        #pragma unroll
        for (int nf = 0; nf < 4; ++nf) acc[nf] = (f32x4){0.f, 0.f, 0.f, 0.f};
        #pragma unroll
        for (int ks = 0; ks < 16; ++ks) {
            union { u32x4 u; bf16x8 v; } au;
            au.u = ha[ks];
            #pragma unroll
            for (int nf = 0; nf < 4; ++nf) {
                bf16x8 b = *(const bf16x8*)(Wl + (nf * 16 + l15) * 520 + ks * 32 + lhi * 8);
                acc[nf] = __builtin_amdgcn_mfma_f32_16x16x32_bf16(au.v, b, acc[nf], 0, 0, 0);
            }
        }
        const uint32_t ep = (uint32_t)(t + 1) << 16;
        #pragma unroll
        for (int q = 0; q < 4; ++q) {
            const int b = w * 16 + lhi * 4 + q;
            float gi = acc[0][q] + bf2f((uint32_t)((xgp[0] >> (16 * q)) & 0xFFFF));
            float gf = acc[1][q] + bf2f((uint32_t)((xgp[1] >> (16 * q)) & 0xFFFF));
            float gg = acc[2][q] + bf2f((uint32_t)((xgp[2] >> (16 * q)) & 0xFFFF));
            float go = acc[3][q] + bf2f((uint32_t)((xgp[3] >> (16 * q)) & 0xFFFF));
            float si = 1.f / (1.f + __expf(-gi));
            float sf = 1.f / (1.f + __expf(-gf));
            float tg = tanhf(gg);
            float so = 1.f / (1.f + __expf(-go));
            float cc = sf * cst[q] + si * tg;
            cst[q] = cc;
            uint16_t hv = f2bf(so * tanhf(cc));
            hs[(size_t)(t * 64 + b) * H_ + u0 + l15] = hv;              // for K3 (plain)
            stsc(hp32 + (t & 1) * (B_ * H_) + (size_t)b * H_ + u0 + l15,
                 ep | (uint32_t)hv);                                     // exchange word
        }
    }
}

// ---------------------------------------------------------------- K3: FC + lse (bf16 MFMA)
// m97-style: tile 128x256, BK=64, 8 waves (wm=w>>2, wn=w&3 -> 64x64/wave).
// global_load_lds width 16, linear LDS, XOR-swizzled source+read (T2/m201):
// LDS[row][slot] holds data seg = slot ^ (row&7)  -> conflict-free ds_read_b128.
// 1D grid 3250, bijective XCD swizzle.
template<int CVT>
__global__ __launch_bounds__(512, 4) void k3_mfma(const uint16_t* __restrict__ hsb,
                                                  const void* __restrict__ fcw,
                                                  const float* __restrict__ fc_b,
                                                  const int* __restrict__ labels,
                                                  float* __restrict__ sumexp,
                                                  float* __restrict__ tgtlog) {
    __shared__ uint16_t Al[128 * 64];   // 16 KB, rows of 128 B
    __shared__ uint16_t Bl[256 * 64];   // 32 KB
    const int flat = blockIdx.x;        // 3250 = 8*406+2: xcd 0,1 get 407
    const int xcd  = flat & 7;
    const int slot = flat >> 3;
    const int work = (xcd < 2 ? xcd * 407 : 814 + (xcd - 2) * 406) + slot;
    const int m0   = (work % 26) * 128;
    const int v0   = (work / 26) * 256;
    const int tid  = threadIdx.x;
    const int w    = tid >> 6;
    const int lane = tid & 63;
    const int l15  = lane & 15;
    const int lhi  = lane >> 4;
    const int wm   = w >> 2;            // 0..1: row half
    const int wn   = w & 3;             // 0..3: col quarter

    f32x4 acc[4][4];
    #pragma unroll
    for (int mi = 0; mi < 4; ++mi)
        #pragma unroll
        for (int nf = 0; nf < 4; ++nf) acc[mi][nf] = (f32x4){0.f, 0.f, 0.f, 0.f};

    const int lrow = lane >> 3;                 // 0..7 within 8-row group
    const int segp = (lane & 7) ^ lrow;         // pre-swizzled source seg

    for (int k0 = 0; k0 < H_; k0 += 64) {
        #pragma unroll
        for (int r = 0; r < 2; ++r) {           // A: 128x64 = 16 wave-insts
            const int g = w * 2 + r, row0 = g * 8;
            int grow = m0 + row0 + lrow; if (grow >= R_) grow = R_ - 1;
            gl_lds16(hsb + (size_t)grow * H_ + k0 + segp * 8, Al + row0 * 64);
        }
        if (CVT == 0) {
            #pragma unroll
            for (int r = 0; r < 4; ++r) {       // B: 256x64 = 32 wave-insts
                const int g = w * 4 + r, row0 = g * 8;
                gl_lds16((const uint16_t*)fcw + (size_t)(v0 + row0 + lrow) * H_ + k0 + segp * 8,
                         Bl + row0 * 64);
            }
        } else {
            #pragma unroll
            for (int r = 0; r < 4; ++r) {       // reg-stage + convert, swizzled write
                int idx = r * 512 + tid, row = idx >> 3, seg = idx & 7;
                const float* s = (const float*)fcw + (size_t)(v0 + row) * H_ + k0 + seg * 8;
                float4 f0 = *(const float4*)s;
                float4 f1 = *(const float4*)(s + 4);
                union { uint16_t h[8]; uint4 u; } p;
                p.h[0]=f2bf(f0.x); p.h[1]=f2bf(f0.y); p.h[2]=f2bf(f0.z); p.h[3]=f2bf(f0.w);
                p.h[4]=f2bf(f1.x); p.h[5]=f2bf(f1.y); p.h[6]=f2bf(f1.z); p.h[7]=f2bf(f1.w);
                *(uint4*)(Bl + row * 64 + (seg ^ (row & 7)) * 8) = p.u;
            }
        }
        __syncthreads();
        #pragma unroll
        for (int ks = 0; ks < 2; ++ks) {
            bf16x8 a[4];
            #pragma unroll
            for (int mi = 0; mi < 4; ++mi) {
                const int ar = wm * 64 + mi * 16 + l15;
                a[mi] = *(const bf16x8*)((const char*)Al + ar * 128 +
                        ((ks * 64 + lhi * 16) ^ ((ar & 7) << 4)));
            }
            #pragma unroll
            for (int nf = 0; nf < 4; ++nf) {
                const int br = wn * 64 + nf * 16 + l15;
                bf16x8 b = *(const bf16x8*)((const char*)Bl + br * 128 +
                           ((ks * 64 + lhi * 16) ^ ((br & 7) << 4)));
                #pragma unroll
                for (int mi = 0; mi < 4; ++mi)
                    acc[mi][nf] = __builtin_amdgcn_mfma_f32_16x16x32_bf16(a[mi], b, acc[mi][nf], 0, 0, 0);
            }
        }
        __syncthreads();
    }
    // epilogue: bias + exp-sum (16-lane shuffle reduce) + target-logit pick
    float bias[4];
    #pragma unroll
    for (int nf = 0; nf < 4; ++nf) bias[nf] = fc_b[v0 + wn * 64 + nf * 16 + l15];
    #pragma unroll
    for (int mi = 0; mi < 4; ++mi) {
        #pragma unroll
        for (int q = 0; q < 4; ++q) {
            const int r = m0 + wm * 64 + mi * 16 + lhi * 4 + q;
            if (r >= R_) continue;
            const int t = r >> 6, b = r & 63;
            const int tgt = (t < 50) ? labels[b * 50 + t] : 2;
            float lsum = 0.f;
            #pragma unroll
            for (int nf = 0; nf < 4; ++nf) {
                const int v = v0 + wn * 64 + nf * 16 + l15;
                float lg = acc[mi][nf][q] + bias[nf];
                lsum += __expf(lg);
                if (v == tgt) tgtlog[r] = lg;
            }
            lsum += __shfl_xor(lsum, 1, 16);
            lsum += __shfl_xor(lsum, 2, 16);
            lsum += __shfl_xor(lsum, 4, 16);
            lsum += __shfl_xor(lsum, 8, 16);
            if (l15 == 0) atomicAdd(&sumexp[r], lsum);
        }
    }
}

// ---------------------------------------------------------------- K4: loss
__global__ __launch_bounds__(256) void k4_loss(const float* __restrict__ sumexp,
                                               const float* __restrict__ tgtlog,
                                               float* __restrict__ out) {
    __shared__ float red[256];
    float s = 0.f;
    for (int r = threadIdx.x; r < R_; r += 256) s += logf(sumexp[r]) - tgtlog[r];
    red[threadIdx.x] = s;
    __syncthreads();
    for (int st = 128; st > 0; st >>= 1) {
        if (threadIdx.x < st) red[threadIdx.x] += red[threadIdx.x + st];
        __syncthreads();
    }
    if (threadIdx.x == 0) out[0] = red[0] / 64.0f;
}

// ----------------------------------------------------------------
extern "C" void kernel_launch(void* const* d_in, const int* in_sizes, int n_in,
                              void* d_out, int out_size, void* d_ws, size_t ws_size,
                              hipStream_t stream) {
    const float* x      = (const float*)d_in[0];
    const int*   labels = (const int*)d_in[1];
    const float* emb    = (const float*)d_in[2];
    const float* W_ih   = (const float*)d_in[3];
    const float* W_hh   = (const float*)d_in[4];
    const float* b_ih   = (const float*)d_in[5];
    const float* b_hh   = (const float*)d_in[6];
    const float* fc_W   = (const float*)d_in[7];
    const float* fc_b   = (const float*)d_in[8];
    float* out = (float*)d_out;

    char* p = (char*)d_ws;
    uint16_t* XgT    = (uint16_t*)p;  p += (size_t)T_ * 512 * 4 * 64 * 2;  // 13.4 MB
    uint16_t* hsb    = (uint16_t*)p;  p += (size_t)R_ * H_ * 2;            // 3.3 MB
    uint16_t* hx     = (uint16_t*)p;  p += (size_t)B_ * H_ * 2;
    float*    sumexp = (float*)p;     p += (size_t)R_ * 4;
    float*    tgtl   = (float*)p;     p += (size_t)R_ * 4;
    uint32_t* hp32   = (uint32_t*)p;  p += (size_t)2 * B_ * H_ * 4;        // 256 KB
    uint16_t* fcwb   = (uint16_t*)p;  p += (size_t)V_ * H_ * 2;            // 32.8 MB
    uint16_t* wihb   = (uint16_t*)p;  p += (size_t)G4_ * H_ * 2;           // 2.1 MB
    const bool pre = ((size_t)(p - (char*)d_ws) <= ws_size);

    k0_init<<<256, 256, 0, stream>>>(x, hx, sumexp, hp32);
    if (pre) {
        kcvt<<<8000, 256, 0, stream>>>(fc_W, fcwb, (V_ * H_) / 8);
        kcvt<<<512, 256, 0, stream>>>(W_ih, wihb, (G4_ * H_) / 8);
        k1_mfma<0><<<dim3(8, 51), 256, 0, stream>>>(labels, emb, wihb, b_ih, b_hh, XgT);
    } else {
        k1_mfma<1><<<dim3(8, 51), 256, 0, stream>>>(labels, emb, W_ih, b_ih, b_hh, XgT);
    }
    k2p<<<32, 256, 0, stream>>>(hx, x, XgT, W_hh, hsb, hp32);
    if (pre) k3_mfma<0><<<3250, 512, 0, stream>>>(hsb, fcwb, fc_b, labels, sumexp, tgtl);
    else     k3_mfma<1><<<3250, 512, 0, stream>>>(hsb, fc_W, fc_b, labels, sumexp, tgtl);
    k4_loss<<<1, 256, 0, stream>>>(sumexp, tgtl, out);
}

// Round 6
// 508.335 us; speedup vs baseline: 1.4732x; 1.3979x over previous
//
#include <hip/hip_runtime.h>
#include <cstddef>
#include <cstdint>

#define B_  64
#define T_  51
#define H_  512
#define G4_ 2048
#define V_  32000
#define R_  (T_ * B_)   // 3264

typedef __attribute__((ext_vector_type(8))) short bf16x8;
typedef __attribute__((ext_vector_type(4))) float f32x4;
typedef __attribute__((ext_vector_type(4))) unsigned int u32x4;
typedef unsigned long long ull;

__device__ __forceinline__ uint16_t f2bf(float f) {   // RNE float->bf16
    uint32_t u = __float_as_uint(f);
    u += 0x7FFFu + ((u >> 16) & 1u);
    return (uint16_t)(u >> 16);
}
__device__ __forceinline__ float bf2f(uint32_t h) { return __uint_as_float(h << 16); }

// LLC-coherent ops (bypass L1+L2, serialize at the device coherence point)
__device__ __forceinline__ void ldsc(u32x4& d, const uint32_t* p) {
    asm volatile("global_load_dwordx4 %0, %1, off sc0 sc1" : "=v"(d) : "v"(p));
}
__device__ __forceinline__ uint32_t ldflag(const uint32_t* p) {
    uint32_t v;
    asm volatile("global_load_dword %0, %1, off sc0 sc1\n\ts_waitcnt vmcnt(0)"
                 : "=v"(v) : "v"(p));
    return v;
}
__device__ __forceinline__ void stflag(uint32_t* p, uint32_t v) {
    asm volatile("global_store_dword %0, %1, off sc0 sc1" :: "v"(p), "v"(v) : "memory");
}
__device__ __forceinline__ void stsh(uint16_t* p, uint32_t v) {   // 2B store
    asm volatile("global_store_short %0, %1, off sc0 sc1" :: "v"(p), "v"(v) : "memory");
}

// async global->LDS, 16B per lane, linear dest
__device__ __forceinline__ void gl_lds16(const void* g, void* l) {
    __builtin_amdgcn_global_load_lds((const __attribute__((address_space(1))) void*)g,
                                     (__attribute__((address_space(3))) void*)l, 16, 0, 0);
}

// ---------------------------------------------------------------- K0: init
// hx = bf16(x); sumexp = 0; wave-flags = 0   (re-run every call: replay-safe)
__global__ __launch_bounds__(256) void k0_init(const float* __restrict__ x,
                                               uint16_t* __restrict__ hx,
                                               float* __restrict__ sumexp,
                                               uint32_t* __restrict__ flags) {
    int i = blockIdx.x * 256 + threadIdx.x;      // 0..32767
    if (i < B_ * H_) hx[i] = f2bf(x[i]);
    if (i < R_) sumexp[i] = 0.f;
    if (i < T_ * 128) flags[i] = 0;
}

// ---------------------------------------------------------------- Kcvt: f32 -> bf16
__global__ __launch_bounds__(256) void kcvt(const float* __restrict__ src,
                                            uint16_t* __restrict__ dst, int n8) {
    int i = blockIdx.x * 256 + threadIdx.x;
    if (i >= n8) return;
    const float4* s = (const float4*)src + (size_t)i * 2;
    float4 f0 = s[0], f1 = s[1];
    union { uint16_t h[8]; uint4 u; } p;
    p.h[0]=f2bf(f0.x); p.h[1]=f2bf(f0.y); p.h[2]=f2bf(f0.z); p.h[3]=f2bf(f0.w);
    p.h[4]=f2bf(f1.x); p.h[5]=f2bf(f1.y); p.h[6]=f2bf(f1.z); p.h[7]=f2bf(f1.w);
    ((uint4*)dst)[i] = p.u;
}

// ---------------------------------------------------------------- K1: Xg GEMM (bf16 MFMA)
// XgT[((t*512+u)*4+g)*64+b] = bf16( emb[tok(r)].W_ih[g*512+u] + b_ih + b_hh )
template<int CVT>
__global__ __launch_bounds__(256, 2) void k1_mfma(const int* __restrict__ labels,
                                                  const float* __restrict__ emb,
                                                  const void* __restrict__ wih,
                                                  const float* __restrict__ b_ih,
                                                  const float* __restrict__ b_hh,
                                                  uint16_t* __restrict__ XgT) {
    __shared__ uint16_t Al[64 * 72];
    __shared__ uint16_t Bl[256 * 72];
    const int t    = blockIdx.y;
    const int n0   = blockIdx.x * 256;
    const int tid  = threadIdx.x;
    const int w    = tid >> 6;
    const int lane = tid & 63;
    const int l15  = lane & 15;
    const int lhi  = lane >> 4;

    f32x4 acc[4][4];
    #pragma unroll
    for (int mi = 0; mi < 4; ++mi)
        #pragma unroll
        for (int nf = 0; nf < 4; ++nf) acc[mi][nf] = (f32x4){0.f, 0.f, 0.f, 0.f};

    for (int k0 = 0; k0 < H_; k0 += 64) {
        #pragma unroll
        for (int r = 0; r < 2; ++r) {       // A: 64x64, gather+convert
            int idx = r * 256 + tid, row = idx >> 3, seg = idx & 7;
            int tok = (t == 0) ? 1 : labels[row * 50 + (t - 1)];
            const float* s = emb + (size_t)tok * H_ + k0 + seg * 8;
            float4 f0 = *(const float4*)s;
            float4 f1 = *(const float4*)(s + 4);
            union { uint16_t h[8]; uint4 u; } p;
            p.h[0]=f2bf(f0.x); p.h[1]=f2bf(f0.y); p.h[2]=f2bf(f0.z); p.h[3]=f2bf(f0.w);
            p.h[4]=f2bf(f1.x); p.h[5]=f2bf(f1.y); p.h[6]=f2bf(f1.z); p.h[7]=f2bf(f1.w);
            *(uint4*)(Al + row * 72 + seg * 8) = p.u;
        }
        #pragma unroll
        for (int r = 0; r < 8; ++r) {       // B: 256x64
            int idx = r * 256 + tid, row = idx >> 3, seg = idx & 7;
            if (CVT) {
                const float* s = (const float*)wih + (size_t)(n0 + row) * H_ + k0 + seg * 8;
                float4 f0 = *(const float4*)s;
                float4 f1 = *(const float4*)(s + 4);
                union { uint16_t h[8]; uint4 u; } p;
                p.h[0]=f2bf(f0.x); p.h[1]=f2bf(f0.y); p.h[2]=f2bf(f0.z); p.h[3]=f2bf(f0.w);
                p.h[4]=f2bf(f1.x); p.h[5]=f2bf(f1.y); p.h[6]=f2bf(f1.z); p.h[7]=f2bf(f1.w);
                *(uint4*)(Bl + row * 72 + seg * 8) = p.u;
            } else {
                *(uint4*)(Bl + row * 72 + seg * 8) =
                    *(const uint4*)((const uint16_t*)wih + (size_t)(n0 + row) * H_ + k0 + seg * 8);
            }
        }
        __syncthreads();
        #pragma unroll
        for (int ks = 0; ks < 2; ++ks) {
            bf16x8 a[4];
            #pragma unroll
            for (int mi = 0; mi < 4; ++mi)
                a[mi] = *(const bf16x8*)(Al + (mi * 16 + l15) * 72 + ks * 32 + lhi * 8);
            #pragma unroll
            for (int nf = 0; nf < 4; ++nf) {
                bf16x8 b = *(const bf16x8*)(Bl + (w * 64 + nf * 16 + l15) * 72 + ks * 32 + lhi * 8);
                #pragma unroll
                for (int mi = 0; mi < 4; ++mi)
                    acc[mi][nf] = __builtin_amdgcn_mfma_f32_16x16x32_bf16(a[mi], b, acc[mi][nf], 0, 0, 0);
            }
        }
        __syncthreads();
    }
    float bias[4];
    #pragma unroll
    for (int nf = 0; nf < 4; ++nf) {
        int col = n0 + w * 64 + nf * 16 + l15;
        bias[nf] = b_ih[col] + b_hh[col];
    }
    #pragma unroll
    for (int mi = 0; mi < 4; ++mi)
        #pragma unroll
        for (int nf = 0; nf < 4; ++nf) {
            const int col = n0 + w * 64 + nf * 16 + l15;
            const int g = col >> 9, u = col & 511;
            const int b = mi * 16 + lhi * 4;
            union { uint16_t h[4]; ull q; } pk;
            #pragma unroll
            for (int q = 0; q < 4; ++q) pk.h[q] = f2bf(acc[mi][nf][q] + bias[nf]);
            *(ull*)(XgT + ((size_t)(t * 512 + u) * 4 + g) * 64 + b) = pk.q;
        }
}

// ---------------------------------------------------------------- K2p: persistent LSTM
// 32 blocks x 4 waves; block owns 16 units; wave w owns batch rows w*16..+15.
// Waves fully autonomous (NO intra-loop __syncthreads). Per step:
//   poll 32 per-wave flags (128B/round) -> 16 pipelined dwordx4 sc0sc1 loads
//   (vmcnt(8)/MFMA/vmcnt(0)/MFMA) -> gates -> 4 stsh -> vmcnt(0) -> 1 flag.
// All exchange at LLC; no fences, no atomics, no L2 flush.
__global__ __launch_bounds__(256, 1) void k2p(const uint16_t* __restrict__ hx,
                                              const float* __restrict__ x,
                                              const uint16_t* __restrict__ XgT,
                                              const float* __restrict__ W_hh,
                                              uint16_t* __restrict__ hs,
                                              uint32_t* __restrict__ flags) {
    __shared__ uint16_t Wl[64 * 520];
    const int tid  = threadIdx.x;
    const int bid  = blockIdx.x;
    const int u0   = bid * 16;
    const int w    = tid >> 6;
    const int lane = tid & 63;
    const int l15  = lane & 15;
    const int lhi  = lane >> 4;
    const int arow = w * 16 + l15;

    {   // W_hh slice -> bf16 LDS. LDS row c = g*16+uu <-> W row g*512+u0+uu
        const int c = tid >> 2;
        const int q = tid & 3;
        const int j = (c >> 4) * 512 + u0 + (c & 15);
        const float* src = W_hh + (size_t)j * H_ + q * 128;
        uint16_t* dst = Wl + c * 520 + q * 128;
        #pragma unroll
        for (int i = 0; i < 128; i += 8) {
            float4 f0 = *(const float4*)(src + i);
            float4 f1 = *(const float4*)(src + i + 4);
            union { uint16_t h[8]; uint4 u; } p;
            p.h[0]=f2bf(f0.x); p.h[1]=f2bf(f0.y); p.h[2]=f2bf(f0.z); p.h[3]=f2bf(f0.w);
            p.h[4]=f2bf(f1.x); p.h[5]=f2bf(f1.y); p.h[6]=f2bf(f1.z); p.h[7]=f2bf(f1.w);
            *(uint4*)(dst + i) = p.u;
        }
    }
    float cst[4];
    #pragma unroll
    for (int q = 0; q < 4; ++q)
        cst[q] = x[(size_t)(w * 16 + lhi * 4 + q) * H_ + u0 + l15];
    __syncthreads();                    // Wl ready (read-only afterwards)

    for (int t = 0; t < T_; ++t) {
        // gate biases for this step (race-free, prefetch before the poll)
        ull xgp[4];
        #pragma unroll
        for (int g = 0; g < 4; ++g)
            xgp[g] = *(const ull*)(XgT + ((size_t)(t * 512 + u0 + l15) * 4 + g) * 64 + w * 16 + lhi * 4);

        u32x4 ha[16];
        if (t == 0) {
            const uint16_t* hb = hx + (size_t)arow * H_ + lhi * 8;
            #pragma unroll
            for (int ks = 0; ks < 16; ++ks)
                ha[ks] = *(const u32x4*)(hb + ks * 32);
        } else {
            // poll the 32 producer-wave flags for (t-1, wave w)
            const uint32_t* fp = flags + (size_t)(t - 1) * 128 + (lane & 31) * 4 + w;
            for (;;) {
                uint32_t fv = 1;
                if (lane < 32) fv = ldflag(fp);
                if (!__any((int)(fv == 0))) break;
            }
            __builtin_amdgcn_sched_barrier(0);
            const uint16_t* hb = hs + ((size_t)(t - 1) * 64 + arow) * H_ + lhi * 8;
            #pragma unroll
            for (int ks = 0; ks < 16; ++ks)
                ldsc(ha[ks], (const uint32_t*)(hb + ks * 32));
        }
        f32x4 acc[4];
        #pragma unroll
        for (int nf = 0; nf < 4; ++nf) acc[nf] = (f32x4){0.f, 0.f, 0.f, 0.f};
        if (t != 0) { asm volatile("s_waitcnt vmcnt(8)" ::: "memory");
                      __builtin_amdgcn_sched_barrier(0); }
        #pragma unroll
        for (int ks = 0; ks < 8; ++ks) {
            union { u32x4 u; bf16x8 v; } au; au.u = ha[ks];
            #pragma unroll
            for (int nf = 0; nf < 4; ++nf) {
                bf16x8 b = *(const bf16x8*)(Wl + (nf * 16 + l15) * 520 + ks * 32 + lhi * 8);
                acc[nf] = __builtin_amdgcn_mfma_f32_16x16x32_bf16(au.v, b, acc[nf], 0, 0, 0);
            }
        }
        if (t != 0) { asm volatile("s_waitcnt vmcnt(0)" ::: "memory");
                      __builtin_amdgcn_sched_barrier(0); }
        #pragma unroll
        for (int ks = 8; ks < 16; ++ks) {
            union { u32x4 u; bf16x8 v; } au; au.u = ha[ks];
            #pragma unroll
            for (int nf = 0; nf < 4; ++nf) {
                bf16x8 b = *(const bf16x8*)(Wl + (nf * 16 + l15) * 520 + ks * 32 + lhi * 8);
                acc[nf] = __builtin_amdgcn_mfma_f32_16x16x32_bf16(au.v, b, acc[nf], 0, 0, 0);
            }
        }
        #pragma unroll
        for (int q = 0; q < 4; ++q) {
            const int b = w * 16 + lhi * 4 + q;
            float gi = acc[0][q] + bf2f((uint32_t)((xgp[0] >> (16 * q)) & 0xFFFF));
            float gf = acc[1][q] + bf2f((uint32_t)((xgp[1] >> (16 * q)) & 0xFFFF));
            float gg = acc[2][q] + bf2f((uint32_t)((xgp[2] >> (16 * q)) & 0xFFFF));
            float go = acc[3][q] + bf2f((uint32_t)((xgp[3] >> (16 * q)) & 0xFFFF));
            float si = 1.f / (1.f + __expf(-gi));
            float sf = 1.f / (1.f + __expf(-gf));
            float tg = tanhf(gg);
            float so = 1.f / (1.f + __expf(-go));
            float cc = sf * cst[q] + si * tg;
            cst[q] = cc;
            stsh(hs + (size_t)(t * 64 + b) * H_ + u0 + l15, (uint32_t)f2bf(so * tanhf(cc)));
        }
        asm volatile("s_waitcnt vmcnt(0)" ::: "memory");   // data stores at LLC
        if (lane == 0) stflag(flags + (size_t)t * 128 + bid * 4 + w, (uint32_t)(t + 1));
    }
}

// ---------------------------------------------------------------- K3: FC + lse (bf16 MFMA)
// m97-style: tile 128x256, BK=64, 8 waves (wm=w>>2, wn=w&3 -> 64x64/wave).
// global_load_lds width 16, XOR-swizzled source+read (T2): conflict-free.
// 1D grid 3250, bijective XCD swizzle.
template<int CVT>
__global__ __launch_bounds__(512, 4) void k3_mfma(const uint16_t* __restrict__ hsb,
                                                  const void* __restrict__ fcw,
                                                  const float* __restrict__ fc_b,
                                                  const int* __restrict__ labels,
                                                  float* __restrict__ sumexp,
                                                  float* __restrict__ tgtlog) {
    __shared__ uint16_t Al[128 * 64];   // 16 KB
    __shared__ uint16_t Bl[256 * 64];   // 32 KB
    const int flat = blockIdx.x;        // 3250 = 8*406+2: xcd 0,1 get 407
    const int xcd  = flat & 7;
    const int slot = flat >> 3;
    const int work = (xcd < 2 ? xcd * 407 : 814 + (xcd - 2) * 406) + slot;
    const int m0   = (work % 26) * 128;
    const int v0   = (work / 26) * 256;
    const int tid  = threadIdx.x;
    const int w    = tid >> 6;
    const int lane = tid & 63;
    const int l15  = lane & 15;
    const int lhi  = lane >> 4;
    const int wm   = w >> 2;
    const int wn   = w & 3;

    f32x4 acc[4][4];
    #pragma unroll
    for (int mi = 0; mi < 4; ++mi)
        #pragma unroll
        for (int nf = 0; nf < 4; ++nf) acc[mi][nf] = (f32x4){0.f, 0.f, 0.f, 0.f};

    const int lrow = lane >> 3;                 // 0..7 within 8-row group
    const int segp = (lane & 7) ^ lrow;         // pre-swizzled source seg

    for (int k0 = 0; k0 < H_; k0 += 64) {
        #pragma unroll
        for (int r = 0; r < 2; ++r) {           // A: 128x64
            const int g = w * 2 + r, row0 = g * 8;
            int grow = m0 + row0 + lrow; if (grow >= R_) grow = R_ - 1;
            gl_lds16(hsb + (size_t)grow * H_ + k0 + segp * 8, Al + row0 * 64);
        }
        if (CVT == 0) {
            #pragma unroll
            for (int r = 0; r < 4; ++r) {       // B: 256x64
                const int g = w * 4 + r, row0 = g * 8;
                gl_lds16((const uint16_t*)fcw + (size_t)(v0 + row0 + lrow) * H_ + k0 + segp * 8,
                         Bl + row0 * 64);
            }
        } else {
            #pragma unroll
            for (int r = 0; r < 4; ++r) {       // reg-stage + convert, swizzled write
                int idx = r * 512 + tid, row = idx >> 3, seg = idx & 7;
                const float* s = (const float*)fcw + (size_t)(v0 + row) * H_ + k0 + seg * 8;
                float4 f0 = *(const float4*)s;
                float4 f1 = *(const float4*)(s + 4);
                union { uint16_t h[8]; uint4 u; } p;
                p.h[0]=f2bf(f0.x); p.h[1]=f2bf(f0.y); p.h[2]=f2bf(f0.z); p.h[3]=f2bf(f0.w);
                p.h[4]=f2bf(f1.x); p.h[5]=f2bf(f1.y); p.h[6]=f2bf(f1.z); p.h[7]=f2bf(f1.w);
                *(uint4*)(Bl + row * 64 + (seg ^ (row & 7)) * 8) = p.u;
            }
        }
        __syncthreads();
        #pragma unroll
        for (int ks = 0; ks < 2; ++ks) {
            bf16x8 a[4];
            #pragma unroll
            for (int mi = 0; mi < 4; ++mi) {
                const int ar = wm * 64 + mi * 16 + l15;
                a[mi] = *(const bf16x8*)((const char*)Al + ar * 128 +
                        ((ks * 64 + lhi * 16) ^ ((ar & 7) << 4)));
            }
            #pragma unroll
            for (int nf = 0; nf < 4; ++nf) {
                const int br = wn * 64 + nf * 16 + l15;
                bf16x8 b = *(const bf16x8*)((const char*)Bl + br * 128 +
                           ((ks * 64 + lhi * 16) ^ ((br & 7) << 4)));
                #pragma unroll
                for (int mi = 0; mi < 4; ++mi)
                    acc[mi][nf] = __builtin_amdgcn_mfma_f32_16x16x32_bf16(a[mi], b, acc[mi][nf], 0, 0, 0);
            }
        }
        __syncthreads();
    }
    float bias[4];
    #pragma unroll
    for (int nf = 0; nf < 4; ++nf) bias[nf] = fc_b[v0 + wn * 64 + nf * 16 + l15];
    #pragma unroll
    for (int mi = 0; mi < 4; ++mi) {
        #pragma unroll
        for (int q = 0; q < 4; ++q) {
            const int r = m0 + wm * 64 + mi * 16 + lhi * 4 + q;
            if (r >= R_) continue;
            const int t = r >> 6, b = r & 63;
            const int tgt = (t < 50) ? labels[b * 50 + t] : 2;
            float lsum = 0.f;
            #pragma unroll
            for (int nf = 0; nf < 4; ++nf) {
                const int v = v0 + wn * 64 + nf * 16 + l15;
                float lg = acc[mi][nf][q] + bias[nf];
                lsum += __expf(lg);
                if (v == tgt) tgtlog[r] = lg;
            }
            lsum += __shfl_xor(lsum, 1, 16);
            lsum += __shfl_xor(lsum, 2, 16);
            lsum += __shfl_xor(lsum, 4, 16);
            lsum += __shfl_xor(lsum, 8, 16);
            if (l15 == 0) atomicAdd(&sumexp[r], lsum);
        }
    }
}

// ---------------------------------------------------------------- K4: loss
__global__ __launch_bounds__(256) void k4_loss(const float* __restrict__ sumexp,
                                               const float* __restrict__ tgtlog,
                                               float* __restrict__ out) {
    __shared__ float red[256];
    float s = 0.f;
    for (int r = threadIdx.x; r < R_; r += 256) s += logf(sumexp[r]) - tgtlog[r];
    red[threadIdx.x] = s;
    __syncthreads();
    for (int st = 128; st > 0; st >>= 1) {
        if (threadIdx.x < st) red[threadIdx.x] += red[threadIdx.x + st];
        __syncthreads();
    }
    if (threadIdx.x == 0) out[0] = red[0] / 64.0f;
}

// ----------------------------------------------------------------
extern "C" void kernel_launch(void* const* d_in, const int* in_sizes, int n_in,
                              void* d_out, int out_size, void* d_ws, size_t ws_size,
                              hipStream_t stream) {
    const float* x      = (const float*)d_in[0];
    const int*   labels = (const int*)d_in[1];
    const float* emb    = (const float*)d_in[2];
    const float* W_ih   = (const float*)d_in[3];
    const float* W_hh   = (const float*)d_in[4];
    const float* b_ih   = (const float*)d_in[5];
    const float* b_hh   = (const float*)d_in[6];
    const float* fc_W   = (const float*)d_in[7];
    const float* fc_b   = (const float*)d_in[8];
    float* out = (float*)d_out;

    char* p = (char*)d_ws;
    uint16_t* XgT    = (uint16_t*)p;  p += (size_t)T_ * 512 * 4 * 64 * 2;  // 13.4 MB
    uint16_t* hsb    = (uint16_t*)p;  p += (size_t)R_ * H_ * 2;            // 3.3 MB
    uint16_t* hx     = (uint16_t*)p;  p += (size_t)B_ * H_ * 2;
    float*    sumexp = (float*)p;     p += (size_t)R_ * 4;
    float*    tgtl   = (float*)p;     p += (size_t)R_ * 4;
    uint32_t* flags  = (uint32_t*)p;  p += (size_t)T_ * 128 * 4 + 256;     // 26 KB
    uint16_t* fcwb   = (uint16_t*)p;  p += (size_t)V_ * H_ * 2;            // 32.8 MB
    uint16_t* wihb   = (uint16_t*)p;  p += (size_t)G4_ * H_ * 2;           // 2.1 MB
    const bool pre = ((size_t)(p - (char*)d_ws) <= ws_size);

    k0_init<<<128, 256, 0, stream>>>(x, hx, sumexp, flags);
    if (pre) {
        kcvt<<<8000, 256, 0, stream>>>(fc_W, fcwb, (V_ * H_) / 8);
        kcvt<<<512, 256, 0, stream>>>(W_ih, wihb, (G4_ * H_) / 8);
        k1_mfma<0><<<dim3(8, 51), 256, 0, stream>>>(labels, emb, wihb, b_ih, b_hh, XgT);
    } else {
        k1_mfma<1><<<dim3(8, 51), 256, 0, stream>>>(labels, emb, W_ih, b_ih, b_hh, XgT);
    }
    k2p<<<32, 256, 0, stream>>>(hx, x, XgT, W_hh, hsb, flags);
    if (pre) k3_mfma<0><<<3250, 512, 0, stream>>>(hsb, fcwb, fc_b, labels, sumexp, tgtl);
    else     k3_mfma<1><<<3250, 512, 0, stream>>>(hsb, fc_W, fc_b, labels, sumexp, tgtl);
    k4_loss<<<1, 256, 0, stream>>>(sumexp, tgtl, out);
}